// Round 7
// baseline (321.685 us; speedup 1.0000x reference)
//
#include <hip/hip_runtime.h>
#include <hip/hip_bf16.h>

#define B_DIM 32
#define C_DIM 512
#define T_IN 1024
#define T_OUT 4096
#define CPB 8  // channels per gather block (32 KiB LDS)

// Native clang vector types (required by nontemporal builtins; also give the
// compiler clean dwordx4 access patterns).
typedef float nfloat4 __attribute__((ext_vector_type(4)));
typedef int nint4 __attribute__((ext_vector_type(4)));

// Kernel 1: per batch row, full cumsum in LDS, then output-centric expansion
// via binary search (uniform control flow, coalesced writes).
__global__ __launch_bounds__(256) void build_idx_kernel(
    const int* __restrict__ dur, int* __restrict__ idx) {
    __shared__ int s_cum[T_IN];   // inclusive cumsum of durations
    __shared__ int s_part[256];

    const int b = blockIdx.x;
    const int tid = threadIdx.x;

    nint4 v = ((const nint4*)(dur + b * T_IN))[tid];
    int c1 = v.x, c2 = c1 + v.y, c3 = c2 + v.z, c4 = c3 + v.w;

    // Hillis-Steele inclusive scan of 256 per-thread totals.
    s_part[tid] = c4;
    __syncthreads();
    #pragma unroll
    for (int off = 1; off < 256; off <<= 1) {
        int val = s_part[tid];
        int add = (tid >= off) ? s_part[tid - off] : 0;
        __syncthreads();
        s_part[tid] = val + add;
        __syncthreads();
    }
    int prefix = s_part[tid] - c4;  // exclusive prefix for this thread

    nint4 cumv;
    cumv.x = prefix + c1;
    cumv.y = prefix + c2;
    cumv.z = prefix + c3;
    cumv.w = prefix + c4;
    ((nint4*)s_cum)[tid] = cumv;
    __syncthreads();

    // j(t) = smallest j with cum[j] > t (searchsorted 'right'). cum[1023] ==
    // T_OUT > t always, so the answer lies in [0, 1023]; lower_bound over
    // interval size 1023 resolves in exactly 10 steps, extras idempotent.
    int* row = idx + b * T_OUT;
    #pragma unroll
    for (int k = 0; k < 16; ++k) {
        const int t = k * 256 + tid;
        int lo = 0, hi = T_IN - 1;
        #pragma unroll
        for (int s = 0; s < 10; ++s) {
            int mid = (lo + hi) >> 1;
            bool gt = s_cum[mid] > t;
            hi = gt ? mid : hi;
            lo = gt ? lo : mid + 1;
        }
        row[t] = lo;
    }
}

// Kernel 2: gather, CPB channels per block. Stage CPB enc rows in LDS via
// async global_load_lds; hoist the whole idx strip (16 ints) to registers;
// then cc-OUTER / g-INNER store order: each wave finishes a contiguous 16 KB
// row region before switching output streams (HBM row locality), with plain
// (non-nt) stores like the 6.4 TB/s fill kernels.
__global__ __launch_bounds__(256) void gather_kernel(
    const float* __restrict__ enc, const int* __restrict__ idx,
    float* __restrict__ out) {
    __shared__ float s_rows[CPB][T_IN];  // 32 KiB

    const int blk = blockIdx.x;          // over B * (C/CPB) = 2048
    const int b = blk >> 6;              // / (C_DIM / CPB = 64)
    const int c0 = (blk & 63) * CPB;
    const int tid = threadIdx.x;

    const float* enc_base = enc + ((size_t)(b * C_DIM + c0)) * T_IN;
    #pragma unroll
    for (int cc = 0; cc < CPB; ++cc) {
        __builtin_amdgcn_global_load_lds(
            (const __attribute__((address_space(1))) void*)
                (enc_base + cc * T_IN + tid * 4),
            (__attribute__((address_space(3))) void*)(&s_rows[cc][tid * 4]),
            16, 0, 0);
    }

    // Hoist all idx loads (overlaps with the async staging above).
    const nint4* idx_row = (const nint4*)(idx + b * T_OUT);  // 1024 int4
    nint4 j[4];
    #pragma unroll
    for (int g = 0; g < 4; ++g) j[g] = idx_row[g * 256 + tid];

    __syncthreads();  // drains vmcnt (incl. global_load_lds)

    float* out_base = out + ((size_t)(b * C_DIM + c0)) * T_OUT;

    #pragma unroll
    for (int cc = 0; cc < CPB; ++cc) {
        nfloat4* orow = (nfloat4*)(out_base + (size_t)cc * T_OUT);
        #pragma unroll
        for (int g = 0; g < 4; ++g) {
            const int t4 = g * 256 + tid;
            nfloat4 o;
            o.x = s_rows[cc][j[g].x];
            o.y = s_rows[cc][j[g].y];
            o.z = s_rows[cc][j[g].z];
            o.w = s_rows[cc][j[g].w];
            orow[t4] = o;
        }
    }
}

extern "C" void kernel_launch(void* const* d_in, const int* in_sizes, int n_in,
                              void* d_out, int out_size, void* d_ws, size_t ws_size,
                              hipStream_t stream) {
    const float* enc = (const float*)d_in[0];   // [B, C, T_IN] f32
    const int* dur = (const int*)d_in[1];       // [B, T_IN] int32
    float* out = (float*)d_out;                 // [B, C, T_OUT] f32
    int* idx = (int*)d_ws;                      // [B, T_OUT] int32 scratch

    build_idx_kernel<<<B_DIM, 256, 0, stream>>>(dur, idx);
    gather_kernel<<<B_DIM * (C_DIM / CPB), 256, 0, stream>>>(enc, idx, out);
}

// Round 8
// 312.223 us; speedup vs baseline: 1.0303x; 1.0303x over previous
//
#include <hip/hip_runtime.h>
#include <hip/hip_bf16.h>

#define B_DIM 32
#define C_DIM 512
#define T_IN 1024
#define T_OUT 4096
#define CPB 4  // channels per gather block (16 KiB LDS) -- best measured (R5)

// Native clang vector types: required by __builtin_nontemporal_load/store
// (HIP_vector_type wrappers are rejected).
typedef float nfloat4 __attribute__((ext_vector_type(4)));
typedef int nint4 __attribute__((ext_vector_type(4)));

// Kernel 1: per batch row, full cumsum in LDS, then output-centric expansion
// via binary search (uniform control flow, coalesced writes).
__global__ __launch_bounds__(256) void build_idx_kernel(
    const int* __restrict__ dur, int* __restrict__ idx) {
    __shared__ int s_cum[T_IN];   // inclusive cumsum of durations
    __shared__ int s_part[256];

    const int b = blockIdx.x;
    const int tid = threadIdx.x;

    nint4 v = ((const nint4*)(dur + b * T_IN))[tid];
    int c1 = v.x, c2 = c1 + v.y, c3 = c2 + v.z, c4 = c3 + v.w;

    // Hillis-Steele inclusive scan of 256 per-thread totals.
    s_part[tid] = c4;
    __syncthreads();
    #pragma unroll
    for (int off = 1; off < 256; off <<= 1) {
        int val = s_part[tid];
        int add = (tid >= off) ? s_part[tid - off] : 0;
        __syncthreads();
        s_part[tid] = val + add;
        __syncthreads();
    }
    int prefix = s_part[tid] - c4;  // exclusive prefix for this thread

    nint4 cumv;
    cumv.x = prefix + c1;
    cumv.y = prefix + c2;
    cumv.z = prefix + c3;
    cumv.w = prefix + c4;
    ((nint4*)s_cum)[tid] = cumv;
    __syncthreads();

    // j(t) = smallest j with cum[j] > t (searchsorted 'right'). cum[1023] ==
    // T_OUT > t for all t in [0, T_OUT), so the answer lies in [0, 1023]:
    // lower_bound over interval size 1023 resolves in exactly 10 steps,
    // extra steps idempotent once lo==hi.
    int* row = idx + b * T_OUT;
    #pragma unroll
    for (int k = 0; k < 16; ++k) {
        const int t = k * 256 + tid;
        int lo = 0, hi = T_IN - 1;
        #pragma unroll
        for (int s = 0; s < 10; ++s) {
            int mid = (lo + hi) >> 1;
            bool gt = s_cum[mid] > t;
            hi = gt ? mid : hi;
            lo = gt ? lo : mid + 1;
        }
        row[t] = lo;
    }
}

// Kernel 2: gather, CPB channels per block (round-5 best config). Stage CPB
// enc rows in LDS (nt vector loads); each idx int4 load feeds CPB gathered
// float4 nt-stores. All global traffic coalesced; data-dependent gather hits
// LDS only (~2-way bank aliasing = free per m136).
__global__ __launch_bounds__(256) void gather_kernel(
    const float* __restrict__ enc, const int* __restrict__ idx,
    float* __restrict__ out) {
    __shared__ float s_rows[CPB][T_IN];  // 16 KiB

    const int blk = blockIdx.x;          // over B * (C/CPB) = 4096
    const int b = blk >> 7;              // / (C_DIM / CPB = 128)
    const int c0 = (blk & 127) * CPB;
    const int tid = threadIdx.x;

    const float* enc_base = enc + ((size_t)(b * C_DIM + c0)) * T_IN;
    #pragma unroll
    for (int cc = 0; cc < CPB; ++cc) {
        nfloat4 v = __builtin_nontemporal_load(
            ((const nfloat4*)(enc_base + cc * T_IN)) + tid);
        ((nfloat4*)s_rows[cc])[tid] = v;
    }
    __syncthreads();

    const nint4* idx_row = (const nint4*)(idx + b * T_OUT);  // 1024 int4
    float* out_base = out + ((size_t)(b * C_DIM + c0)) * T_OUT;

    #pragma unroll
    for (int g = 0; g < 4; ++g) {
        const int t4 = g * 256 + tid;
        nint4 j = idx_row[t4];
        #pragma unroll
        for (int cc = 0; cc < CPB; ++cc) {
            nfloat4 o;
            o.x = s_rows[cc][j.x];
            o.y = s_rows[cc][j.y];
            o.z = s_rows[cc][j.z];
            o.w = s_rows[cc][j.w];
            __builtin_nontemporal_store(
                o, ((nfloat4*)(out_base + (size_t)cc * T_OUT)) + t4);
        }
    }
}

extern "C" void kernel_launch(void* const* d_in, const int* in_sizes, int n_in,
                              void* d_out, int out_size, void* d_ws, size_t ws_size,
                              hipStream_t stream) {
    const float* enc = (const float*)d_in[0];   // [B, C, T_IN] f32
    const int* dur = (const int*)d_in[1];       // [B, T_IN] int32
    float* out = (float*)d_out;                 // [B, C, T_OUT] f32
    int* idx = (int*)d_ws;                      // [B, T_OUT] int32 scratch

    build_idx_kernel<<<B_DIM, 256, 0, stream>>>(dur, idx);
    gather_kernel<<<B_DIM * (C_DIM / CPB), 256, 0, stream>>>(enc, idx, out);
}